// Round 4
// baseline (1246.475 us; speedup 1.0000x reference)
//
#include <hip/hip_runtime.h>

// Two-hop SpMM-mean. Round 4: two-level scatter to kill random-write sector
// amplification (125 MB -> ~28 MB per hop).
//   scatter_bins: bin = row>>6; bin region = [row_off[b*64], ...) (exact, from
//     row_off). Atomic bin cursor; stage (row,col)+val appended to bin tails
//     -> L2 fills sectors completely before eviction.
//   sort_bins: one WG per bin; per-row LDS cursors; writes final (col,val)
//     into the bin's contiguous region -> full-sector writebacks.

#define DIM 64
#define RPB 64          // rows per bin (power of two)
#define RPB_SHIFT 6

__global__ void hist_kernel(const int* __restrict__ rows, int nnz,
                            int* __restrict__ counts) {
    int i = blockIdx.x * blockDim.x + threadIdx.x;
    if (i < nnz) atomicAdd(&counts[rows[i]], 1);
}

__global__ void scan_blocks_kernel(const int* __restrict__ in, int n,
                                   int* __restrict__ out,
                                   int* __restrict__ block_sums) {
    __shared__ int s[256];
    int t = threadIdx.x;
    int i = blockIdx.x * 256 + t;
    int x = (i < n) ? in[i] : 0;
    s[t] = x;
    __syncthreads();
    for (int off = 1; off < 256; off <<= 1) {
        int v = (t >= off) ? s[t - off] : 0;
        __syncthreads();
        s[t] += v;
        __syncthreads();
    }
    if (i < n) out[i] = s[t] - x;          // exclusive
    if (t == 255) block_sums[blockIdx.x] = s[255];
}

__global__ void scan_sums_kernel(int* __restrict__ sums, int n) {
    __shared__ int s[512];
    int t = threadIdx.x;
    int x = (t < n) ? sums[t] : 0;
    s[t] = x;
    __syncthreads();
    for (int off = 1; off < 512; off <<= 1) {
        int v = (t >= off) ? s[t - off] : 0;
        __syncthreads();
        s[t] += v;
        __syncthreads();
    }
    if (t < n) sums[t] = s[t] - x;         // exclusive
}

__global__ void add_offsets_kernel(int* __restrict__ out,
                                   const int* __restrict__ sums, int n) {
    int i = blockIdx.x * 256 + threadIdx.x;
    if (i < n) out[i] += sums[blockIdx.x];
}

// Level 1: append each edge to its bin's staging tail (clustered writes).
__global__ void scatter_bins_kernel(const int* __restrict__ rows,
                                    const int* __restrict__ cols,
                                    const float* __restrict__ vals,
                                    const int* __restrict__ row_off,
                                    int* __restrict__ bincur,     // zeroed, NB ints
                                    int2* __restrict__ st_rc,     // staged (row,col)
                                    float* __restrict__ st_val,   // staged val
                                    int nnz) {
    int i = blockIdx.x * blockDim.x + threadIdx.x;
    if (i >= nnz) return;
    int r = rows[i];
    int b = r >> RPB_SHIFT;
    int base = row_off[r & ~(RPB - 1)];        // bin region start (exact)
    int pos = base + atomicAdd(&bincur[b], 1);
    st_rc[pos]  = make_int2(r, cols[i]);
    st_val[pos] = vals[i];
}

// Level 2: one workgroup per bin; exact within-bin sort by row via LDS cursors.
__global__ void sort_bins_kernel(const int2* __restrict__ st_rc,
                                 const float* __restrict__ st_val,
                                 const int* __restrict__ row_off,
                                 int2* __restrict__ colval,
                                 int n_rows, int nnz) {
    __shared__ int lcur[RPB];
    int b = blockIdx.x;
    int row0 = b << RPB_SHIFT;
    int start = row_off[row0];
    int re = row0 + RPB;
    int end = (re < n_rows) ? row_off[re] : nnz;
    for (int t = threadIdx.x; t < RPB; t += blockDim.x) lcur[t] = 0;
    __syncthreads();
    for (int i = start + threadIdx.x; i < end; i += blockDim.x) {
        int2 rc = st_rc[i];
        float v = st_val[i];
        int rank = atomicAdd(&lcur[rc.x & (RPB - 1)], 1);
        colval[row_off[rc.x] + rank] = make_int2(rc.y, __float_as_int(v));
    }
}

// One wave per row. lane = 16*sub + ld: sub = edge slot, ld = float4 chunk.
__global__ void gather_rows_kernel(const int2* __restrict__ colval,
                                   const int* __restrict__ row_off,
                                   const float* __restrict__ src,   // [n_src,64]
                                   float* __restrict__ dst,         // [n_rows,64]
                                   int n_rows, int nnz) {
    int wave = (blockIdx.x * blockDim.x + threadIdx.x) >> 6;
    int lane = threadIdx.x & 63;
    if (wave >= n_rows) return;
    int sub = lane >> 4;
    int ld  = lane & 15;
    int start = row_off[wave];
    int end   = (wave + 1 < n_rows) ? row_off[wave + 1] : nnz;

    float ax = 0.f, ay = 0.f, az = 0.f, aw = 0.f;
    float vsum = 0.0f;
    for (int i = start; i < end; i += 4) {
        int idx = i + sub;
        int c = 0; float v = 0.0f;
        if (idx < end) {
            int2 cv = colval[idx];
            c = cv.x;
            v = __int_as_float(cv.y);
        }
        const float4 x = *(const float4*)(src + (long long)c * DIM + ld * 4);
        ax += v * x.x; ay += v * x.y; az += v * x.z; aw += v * x.w;
        vsum += v;
    }
    #pragma unroll
    for (int off = 16; off <= 32; off <<= 1) {
        ax += __shfl_xor(ax, off);
        ay += __shfl_xor(ay, off);
        az += __shfl_xor(az, off);
        aw += __shfl_xor(aw, off);
        vsum += __shfl_xor(vsum, off);
    }
    float d = (vsum == 0.0f) ? 1.0f : vsum;
    if (sub == 0) {
        float inv = 1.0f / d;
        float4 o = make_float4(ax * inv, ay * inv, az * inv, aw * inv);
        *(float4*)(dst + (long long)wave * DIM + ld * 4) = o;
    }
}

static void run_hop(const int* rows, const int* cols, const float* vals,
                    int nnz, int n_rows,
                    const float* src, float* dst,
                    int* row_off, int* counts, int* block_sums, int* bincur,
                    int2* st_rc, float* st_val, int2* colval,
                    hipStream_t stream) {
    const int B = 256;
    int nblocks = (n_rows + B - 1) / B;
    int nb = (n_rows + RPB - 1) >> RPB_SHIFT;

    hipMemsetAsync(counts, 0, (size_t)n_rows * sizeof(int), stream);
    hist_kernel<<<(nnz + B - 1) / B, B, 0, stream>>>(rows, nnz, counts);

    scan_blocks_kernel<<<nblocks, B, 0, stream>>>(counts, n_rows, row_off, block_sums);
    scan_sums_kernel<<<1, 512, 0, stream>>>(block_sums, nblocks);
    add_offsets_kernel<<<nblocks, B, 0, stream>>>(row_off, block_sums, n_rows);

    hipMemsetAsync(bincur, 0, (size_t)nb * sizeof(int), stream);
    scatter_bins_kernel<<<(nnz + B - 1) / B, B, 0, stream>>>(
        rows, cols, vals, row_off, bincur, st_rc, st_val, nnz);
    sort_bins_kernel<<<nb, B, 0, stream>>>(st_rc, st_val, row_off, colval,
                                           n_rows, nnz);

    int gblocks = (n_rows + 3) / 4;   // 4 waves (rows) per 256-thread block
    gather_rows_kernel<<<gblocks, B, 0, stream>>>(colval, row_off,
                                                  src, dst, n_rows, nnz);
}

extern "C" void kernel_launch(void* const* d_in, const int* in_sizes, int n_in,
                              void* d_out, int out_size, void* d_ws, size_t ws_size,
                              hipStream_t stream) {
    const float* item_emb = (const float*)d_in[1];
    const int*   hv_rows  = (const int*)d_in[2];
    const int*   hv_cols  = (const int*)d_in[3];
    const float* hv_vals  = (const float*)d_in[4];
    const int*   hu_rows  = (const int*)d_in[5];
    const int*   hu_cols  = (const int*)d_in[6];
    const float* hu_vals  = (const float*)d_in[7];

    const int nnz1 = in_sizes[2];
    const int nnz2 = in_sizes[5];
    const int n_b  = 50000;
    const int n_u  = out_size / DIM;

    float* out = (float*)d_out;

    // Workspace layout (all region sizes multiples of 16 B for these dims)
    char* p = (char*)d_ws;
    float* bf         = (float*)p; p += (size_t)n_b * DIM * sizeof(float); // 12.8 MB
    int*   row_off1   = (int*)p;   p += (size_t)n_b * sizeof(int);
    int*   row_off2   = (int*)p;   p += (size_t)n_u * sizeof(int);
    int*   counts     = (int*)p;   p += (size_t)n_u * sizeof(int);         // max(n_b,n_u)
    int*   block_sums = (int*)p;   p += 512 * sizeof(int);
    int*   bincur     = (int*)p;   p += 2048 * sizeof(int);                // max NB=1563
    int2*  st_rc      = (int2*)p;  p += (size_t)nnz1 * sizeof(int2);       // 16 MB
    float* st_val     = (float*)p; p += (size_t)nnz1 * sizeof(float);      // 8 MB
    int2*  colval     = (int2*)p;  p += (size_t)nnz1 * sizeof(int2);       // 16 MB

    // Hop 1: item_emb -> bf
    run_hop(hv_rows, hv_cols, hv_vals, nnz1, n_b, item_emb, bf,
            row_off1, counts, block_sums, bincur, st_rc, st_val, colval, stream);
    // Hop 2: bf -> out
    run_hop(hu_rows, hu_cols, hu_vals, nnz2, n_u, bf, out,
            row_off2, counts, block_sums, bincur, st_rc, st_val, colval, stream);
}

// Round 5
// 428.202 us; speedup vs baseline: 2.9110x; 2.9110x over previous
//
#include <hip/hip_runtime.h>

// Two-hop SpMM-mean. Round 5: WG-aggregated two-level binning.
//  - pass1_bin: each WG (8192-edge chunk) histograms bins in LDS, reserves
//    per-bin ranges with ONE global fetch-add per (WG,bin), then writes its
//    edges as contiguous per-bin runs (single-XCD writers -> full sectors).
//    Staged record packed 8B: key = (rowlocal<<17)|col, val.
//  - bin_scan: 391-entry exclusive scan of bin counts -> global bin bases.
//  - pass2_sort: one WG per bin; LDS per-row counts + LDS scan -> emits
//    global row_off AND final (col,val) sorted by row. No 100K-row
//    histogram/scan kernels, no per-edge global atomics anywhere.
//  - gather_rows: unchanged from round 3 (wave per row, 4 edges in flight,
//    float4 row reads, fused mean).

#define DIM 64
#define NB_MAX 400
#define CAP 5888          // per-bin staging capacity (mean 5115, +10.8 sigma)
#define CHUNK 8192        // edges per pass1 workgroup

__global__ void pass1_bin_kernel(const int* __restrict__ rows,
                                 const int* __restrict__ cols,
                                 const float* __restrict__ vals,
                                 int nnz, int shift, int nb,
                                 int* __restrict__ bincnt,   // zeroed, nb ints
                                 int2* __restrict__ st) {    // nb*CAP records
    __shared__ int hist[NB_MAX];
    __shared__ int cur[NB_MAX];
    int t = threadIdx.x;
    for (int i = t; i < nb; i += 256) hist[i] = 0;
    __syncthreads();
    int begin = blockIdx.x * CHUNK;
    int endc  = begin + CHUNK; if (endc > nnz) endc = nnz;
    for (int i = begin + t; i < endc; i += 256)
        atomicAdd(&hist[rows[i] >> shift], 1);
    __syncthreads();
    for (int i = t; i < nb; i += 256) {
        int h = hist[i];
        if (h > 0) cur[i] = i * CAP + atomicAdd(&bincnt[i], h);
    }
    __syncthreads();
    for (int i = begin + t; i < endc; i += 256) {
        int r = rows[i];
        int b = r >> shift;
        int pos = atomicAdd(&cur[b], 1);           // LDS atomic
        int key = ((r - (b << shift)) << 17) | cols[i];
        st[pos] = make_int2(key, __float_as_int(vals[i]));
    }
}

// Exclusive scan of bincnt[0..nb) -> bin_base. nb <= 512, single WG.
__global__ void bin_scan_kernel(const int* __restrict__ bincnt,
                                int* __restrict__ bin_base, int nb) {
    __shared__ int s[512];
    int t = threadIdx.x;
    int x = (t < nb) ? bincnt[t] : 0;
    s[t] = x;
    __syncthreads();
    for (int off = 1; off < 512; off <<= 1) {
        int v = (t >= off) ? s[t - off] : 0;
        __syncthreads();
        s[t] += v;
        __syncthreads();
    }
    if (t < nb) bin_base[t] = s[t] - x;
}

// One WG per bin: count rows in LDS, scan, emit row_off + sorted (col,val).
template <int RPB>
__global__ void pass2_sort_kernel(const int2* __restrict__ st,
                                  const int* __restrict__ bincnt,
                                  const int* __restrict__ bin_base,
                                  int n_rows,
                                  int* __restrict__ row_off,
                                  int2* __restrict__ colval) {
    __shared__ int cnt[RPB];
    __shared__ int scn[RPB];
    int b = blockIdx.x;
    int t = threadIdx.x;                 // 256 threads
    int row0 = b * RPB;
    int nrows = n_rows - row0; if (nrows > RPB) nrows = RPB;
    int cnt_b = bincnt[b];
    int base  = bin_base[b];
    const int2* bst = st + (size_t)b * CAP;

    for (int i = t; i < RPB; i += 256) cnt[i] = 0;
    __syncthreads();
    for (int i = t; i < cnt_b; i += 256)
        atomicAdd(&cnt[bst[i].x >> 17], 1);
    __syncthreads();
    // inclusive scan of cnt into scn (RPB <= blockDim)
    for (int i = t; i < RPB; i += 256) scn[i] = cnt[i];
    __syncthreads();
    for (int off = 1; off < RPB; off <<= 1) {
        int v = 0;
        if (t < RPB && t >= off) v = scn[t - off];
        __syncthreads();
        if (t < RPB) scn[t] += v;
        __syncthreads();
    }
    // row_off + cursors (exclusive = inclusive - cnt)
    for (int i = t; i < RPB; i += 256) {
        int excl = base + scn[i] - cnt[i];
        if (i < nrows) row_off[row0 + i] = excl;
        cnt[i] = excl;                    // reuse cnt[] as write cursor
    }
    __syncthreads();
    for (int i = t; i < cnt_b; i += 256) {
        int2 kv = bst[i];
        int pos = atomicAdd(&cnt[kv.x >> 17], 1);   // LDS atomic
        colval[pos] = make_int2(kv.x & 0x1FFFF, kv.y);
    }
}

// One wave per row. lane = 16*sub + ld: sub = edge slot, ld = float4 chunk.
__global__ void gather_rows_kernel(const int2* __restrict__ colval,
                                   const int* __restrict__ row_off,
                                   const float* __restrict__ src,   // [n_src,64]
                                   float* __restrict__ dst,         // [n_rows,64]
                                   int n_rows, int nnz) {
    int wave = (blockIdx.x * blockDim.x + threadIdx.x) >> 6;
    int lane = threadIdx.x & 63;
    if (wave >= n_rows) return;
    int sub = lane >> 4;
    int ld  = lane & 15;
    int start = row_off[wave];
    int end   = (wave + 1 < n_rows) ? row_off[wave + 1] : nnz;

    float ax = 0.f, ay = 0.f, az = 0.f, aw = 0.f;
    float vsum = 0.0f;
    for (int i = start; i < end; i += 4) {
        int idx = i + sub;
        int c = 0; float v = 0.0f;
        if (idx < end) {
            int2 cv = colval[idx];
            c = cv.x;
            v = __int_as_float(cv.y);
        }
        const float4 x = *(const float4*)(src + (long long)c * DIM + ld * 4);
        ax += v * x.x; ay += v * x.y; az += v * x.z; aw += v * x.w;
        vsum += v;
    }
    #pragma unroll
    for (int off = 16; off <= 32; off <<= 1) {
        ax += __shfl_xor(ax, off);
        ay += __shfl_xor(ay, off);
        az += __shfl_xor(az, off);
        aw += __shfl_xor(aw, off);
        vsum += __shfl_xor(vsum, off);
    }
    float d = (vsum == 0.0f) ? 1.0f : vsum;
    if (sub == 0) {
        float inv = 1.0f / d;
        float4 o = make_float4(ax * inv, ay * inv, az * inv, aw * inv);
        *(float4*)(dst + (long long)wave * DIM + ld * 4) = o;
    }
}

template <int RPB, int SHIFT>
static void run_hop(const int* rows, const int* cols, const float* vals,
                    int nnz, int n_rows,
                    const float* src, float* dst,
                    int* bincnt, int* bin_base, int* row_off,
                    int2* st, int2* colval, hipStream_t stream) {
    const int B = 256;
    int nb = (n_rows + RPB - 1) / RPB;

    hipMemsetAsync(bincnt, 0, (size_t)nb * sizeof(int), stream);
    int p1blocks = (nnz + CHUNK - 1) / CHUNK;
    pass1_bin_kernel<<<p1blocks, B, 0, stream>>>(rows, cols, vals, nnz, SHIFT,
                                                 nb, bincnt, st);
    bin_scan_kernel<<<1, 512, 0, stream>>>(bincnt, bin_base, nb);
    pass2_sort_kernel<RPB><<<nb, B, 0, stream>>>(st, bincnt, bin_base, n_rows,
                                                 row_off, colval);
    int gblocks = (n_rows + 3) / 4;   // 4 waves (rows) per 256-thread block
    gather_rows_kernel<<<gblocks, B, 0, stream>>>(colval, row_off,
                                                  src, dst, n_rows, nnz);
}

extern "C" void kernel_launch(void* const* d_in, const int* in_sizes, int n_in,
                              void* d_out, int out_size, void* d_ws, size_t ws_size,
                              hipStream_t stream) {
    const float* item_emb = (const float*)d_in[1];
    const int*   hv_rows  = (const int*)d_in[2];
    const int*   hv_cols  = (const int*)d_in[3];
    const float* hv_vals  = (const float*)d_in[4];
    const int*   hu_rows  = (const int*)d_in[5];
    const int*   hu_cols  = (const int*)d_in[6];
    const float* hu_vals  = (const float*)d_in[7];

    const int nnz1 = in_sizes[2];
    const int nnz2 = in_sizes[5];
    const int n_b  = 50000;
    const int n_u  = out_size / DIM;

    float* out = (float*)d_out;

    // Workspace (~47.7 MB): buffers reused across the two sequential hops.
    char* p = (char*)d_ws;
    float* bf       = (float*)p; p += (size_t)n_b * DIM * sizeof(float);   // 12.8 MB
    int*   row_off  = (int*)p;   p += (size_t)n_u * sizeof(int);           // 0.4 MB
    int*   bincnt   = (int*)p;   p += NB_MAX * sizeof(int);
    int*   bin_base = (int*)p;   p += NB_MAX * sizeof(int);
    int2*  st       = (int2*)p;  p += (size_t)NB_MAX * CAP * sizeof(int2); // 18.8 MB
    int2*  colval   = (int2*)p;  p += (size_t)nnz1 * sizeof(int2);         // 16 MB

    // Hop 1: item_emb -> bf   (50000 rows, RPB=128 -> 391 bins)
    run_hop<128, 7>(hv_rows, hv_cols, hv_vals, nnz1, n_b, item_emb, bf,
                    bincnt, bin_base, row_off, st, colval, stream);
    // Hop 2: bf -> out        (100000 rows, RPB=256 -> 391 bins)
    run_hop<256, 8>(hu_rows, hu_cols, hu_vals, nnz2, n_u, bf, out,
                    bincnt, bin_base, row_off, st, colval, stream);
}

// Round 6
// 284.502 us; speedup vs baseline: 4.3813x; 1.5051x over previous
//
#include <hip/hip_runtime.h>

// Two-hop SpMM-mean. Round 6: 3-kernel pipeline.
//  - pass1_bin (fused both hops, block=512, reg-cached edges): LDS histogram
//    per 8192-edge chunk, ONE global fetch-add per (WG,bin), contiguous
//    per-bin runs (~21 rec = 168B -> near-full sectors).
//  - sort_gather (per bin, block=1024): count+scan+scatter bin's edges into
//    LDS (sorted by row), then gather directly from LDS edge list.
//    No global colval, no row_off, no bin_scan. 8 edges in flight per wave.

#define DIM 64
#define CAP 5888          // per-bin staging capacity (mean 5120, +10.7 sigma)
#define CHUNK 8192        // edges per pass1 workgroup
#define P1B 512
#define EPT (CHUNK / P1B) // 16 edges per thread
#define NB1 391           // ceil(50000/128)
#define NB2 391           // ceil(100000/256)

__global__ __launch_bounds__(P1B) void pass1_bin_kernel(
    const int* __restrict__ rows1, const int* __restrict__ cols1,
    const float* __restrict__ vals1, int nnz1, int nc1,
    const int* __restrict__ rows2, const int* __restrict__ cols2,
    const float* __restrict__ vals2, int nnz2,
    int* __restrict__ bincnt1, int2* __restrict__ st1,
    int* __restrict__ bincnt2, int2* __restrict__ st2) {
    __shared__ int hist[400];
    __shared__ int cur[400];
    const int* rows; const int* cols; const float* vals;
    int nnz, shift, nb, chunk_id;
    int* bincnt; int2* st;
    if ((int)blockIdx.x < nc1) {
        rows = rows1; cols = cols1; vals = vals1; nnz = nnz1;
        shift = 7; nb = NB1; chunk_id = blockIdx.x; bincnt = bincnt1; st = st1;
    } else {
        rows = rows2; cols = cols2; vals = vals2; nnz = nnz2;
        shift = 8; nb = NB2; chunk_id = blockIdx.x - nc1; bincnt = bincnt2; st = st2;
    }
    int t = threadIdx.x;
    for (int i = t; i < nb; i += P1B) hist[i] = 0;
    __syncthreads();
    int begin = chunk_id * CHUNK;

    int r[EPT]; int c[EPT]; float v[EPT];
    #pragma unroll
    for (int k = 0; k < EPT; ++k) {
        int idx = begin + k * P1B + t;
        bool ok = idx < nnz;
        r[k] = ok ? rows[idx] : -1;
        c[k] = ok ? cols[idx] : 0;
        v[k] = ok ? vals[idx] : 0.0f;
        if (ok) atomicAdd(&hist[r[k] >> shift], 1);
    }
    __syncthreads();
    for (int i = t; i < nb; i += P1B) {
        int h = hist[i];
        if (h > 0) cur[i] = i * CAP + atomicAdd(&bincnt[i], h);
    }
    __syncthreads();
    #pragma unroll
    for (int k = 0; k < EPT; ++k) {
        if (r[k] >= 0) {
            int b = r[k] >> shift;
            int pos = atomicAdd(&cur[b], 1);       // LDS atomic
            int key = ((r[k] - (b << shift)) << 17) | c[k];
            st[pos] = make_int2(key, __float_as_int(v[k]));
        }
    }
}

// One WG per bin: LDS sort by row, then gather from LDS edge list.
template <int RPB>
__global__ __launch_bounds__(1024, 8) void sort_gather_kernel(
    const int2* __restrict__ st, const int* __restrict__ bincnt,
    const float* __restrict__ src,   // [n_src, 64]
    float* __restrict__ dst,         // [n_rows, 64]
    int n_rows) {
    __shared__ int2 edges[CAP];
    __shared__ int excl[RPB];        // row start (within LDS edges[])
    __shared__ int cur[RPB];         // cursor; after scatter = row end
    int b = blockIdx.x;
    int t = threadIdx.x;
    int row0 = b * RPB;
    int cnt_b = bincnt[b];
    const int2* bst = st + (size_t)b * CAP;

    if (t < RPB) cur[t] = 0;
    __syncthreads();
    // count rows
    for (int i = t; i < cnt_b; i += 1024)
        atomicAdd(&cur[bst[i].x >> 17], 1);
    __syncthreads();
    // inclusive scan of counts into excl[]
    if (t < RPB) excl[t] = cur[t];
    __syncthreads();
    for (int off = 1; off < RPB; off <<= 1) {
        int vv = 0;
        if (t < RPB && t >= off) vv = excl[t - off];
        __syncthreads();
        if (t < RPB) excl[t] += vv;
        __syncthreads();
    }
    // exclusive offsets + cursors
    if (t < RPB) {
        int e = excl[t] - cur[t];
        excl[t] = e;
        cur[t] = e;
    }
    __syncthreads();
    // scatter into sorted LDS order
    for (int i = t; i < cnt_b; i += 1024) {
        int2 kv = bst[i];
        int pos = atomicAdd(&cur[kv.x >> 17], 1);   // LDS atomic
        edges[pos] = make_int2(kv.x & 0x1FFFF, kv.y);
    }
    __syncthreads();
    // gather: one wave per row, 16 waves/WG; 8 edges in flight
    int wave = t >> 6;
    int lane = t & 63;
    int sub = lane >> 4;     // edge slot 0..3
    int ld  = lane & 15;     // float4 chunk
    for (int rl = wave; rl < RPB; rl += 16) {
        int row = row0 + rl;
        if (row >= n_rows) break;
        int start = excl[rl];
        int end   = cur[rl];
        float ax = 0.f, ay = 0.f, az = 0.f, aw = 0.f, vsum = 0.f;
        for (int i = start; i < end; i += 8) {
            int i0 = i + sub, i1 = i + sub + 4;
            int c0 = 0, c1 = 0; float v0 = 0.f, v1 = 0.f;
            if (i0 < end) { int2 e = edges[i0]; c0 = e.x; v0 = __int_as_float(e.y); }
            if (i1 < end) { int2 e = edges[i1]; c1 = e.x; v1 = __int_as_float(e.y); }
            const float4 x0 = *(const float4*)(src + (long long)c0 * DIM + ld * 4);
            const float4 x1 = *(const float4*)(src + (long long)c1 * DIM + ld * 4);
            ax += v0 * x0.x + v1 * x1.x;
            ay += v0 * x0.y + v1 * x1.y;
            az += v0 * x0.z + v1 * x1.z;
            aw += v0 * x0.w + v1 * x1.w;
            vsum += v0 + v1;
        }
        #pragma unroll
        for (int off = 16; off <= 32; off <<= 1) {
            ax += __shfl_xor(ax, off);
            ay += __shfl_xor(ay, off);
            az += __shfl_xor(az, off);
            aw += __shfl_xor(aw, off);
            vsum += __shfl_xor(vsum, off);
        }
        float d = (vsum == 0.0f) ? 1.0f : vsum;
        if (sub == 0) {
            float inv = 1.0f / d;
            float4 o = make_float4(ax * inv, ay * inv, az * inv, aw * inv);
            *(float4*)(dst + (long long)row * DIM + ld * 4) = o;
        }
    }
}

extern "C" void kernel_launch(void* const* d_in, const int* in_sizes, int n_in,
                              void* d_out, int out_size, void* d_ws, size_t ws_size,
                              hipStream_t stream) {
    const float* item_emb = (const float*)d_in[1];
    const int*   hv_rows  = (const int*)d_in[2];
    const int*   hv_cols  = (const int*)d_in[3];
    const float* hv_vals  = (const float*)d_in[4];
    const int*   hu_rows  = (const int*)d_in[5];
    const int*   hu_cols  = (const int*)d_in[6];
    const float* hu_vals  = (const float*)d_in[7];

    const int nnz1 = in_sizes[2];
    const int nnz2 = in_sizes[5];
    const int n_b  = 50000;
    const int n_u  = out_size / DIM;

    float* out = (float*)d_out;

    // Workspace (~49.7 MB)
    char* p = (char*)d_ws;
    float* bf      = (float*)p; p += (size_t)n_b * DIM * sizeof(float);    // 12.8 MB
    int*   bincnt1 = (int*)p;   p += 400 * sizeof(int);
    int*   bincnt2 = (int*)p;   p += 400 * sizeof(int);
    int2*  st1     = (int2*)p;  p += (size_t)NB1 * CAP * sizeof(int2);     // 18.4 MB
    int2*  st2     = (int2*)p;  p += (size_t)NB2 * CAP * sizeof(int2);     // 18.4 MB

    hipMemsetAsync(bincnt1, 0, 800 * sizeof(int), stream);

    int nc1 = (nnz1 + CHUNK - 1) / CHUNK;
    int nc2 = (nnz2 + CHUNK - 1) / CHUNK;
    pass1_bin_kernel<<<nc1 + nc2, P1B, 0, stream>>>(
        hv_rows, hv_cols, hv_vals, nnz1, nc1,
        hu_rows, hu_cols, hu_vals, nnz2,
        bincnt1, st1, bincnt2, st2);

    // Hop 1: item_emb -> bf   (50000 rows, 128 rows/bin)
    sort_gather_kernel<128><<<NB1, 1024, 0, stream>>>(st1, bincnt1, item_emb, bf, n_b);
    // Hop 2: bf -> out        (100000 rows, 256 rows/bin)
    sort_gather_kernel<256><<<NB2, 1024, 0, stream>>>(st2, bincnt2, bf, out, n_u);
}

// Round 7
// 251.756 us; speedup vs baseline: 4.9511x; 1.1301x over previous
//
#include <hip/hip_runtime.h>
#include <hip/hip_fp16.h>

// Two-hop SpMM-mean. Round 7: fp16 gathered tables (fp32 math).
//  - convert item_emb fp32->fp16 (12.8 MB); hop1 writes bf as fp16 (6.4 MB).
//    Halves the 512 MB/hop gather stream AND the L2 working set.
//  - pass1_bin / sort structure unchanged from round 6.

#define DIM 64
#define CAP 5888          // per-bin staging capacity (mean 5120, +10.7 sigma)
#define CHUNK 8192        // edges per pass1 workgroup
#define P1B 512
#define EPT (CHUNK / P1B) // 16 edges per thread
#define NB1 391           // ceil(50000/128)
#define NB2 391           // ceil(100000/256)

__global__ __launch_bounds__(P1B) void pass1_bin_kernel(
    const int* __restrict__ rows1, const int* __restrict__ cols1,
    const float* __restrict__ vals1, int nnz1, int nc1,
    const int* __restrict__ rows2, const int* __restrict__ cols2,
    const float* __restrict__ vals2, int nnz2,
    int* __restrict__ bincnt1, int2* __restrict__ st1,
    int* __restrict__ bincnt2, int2* __restrict__ st2) {
    __shared__ int hist[400];
    __shared__ int cur[400];
    const int* rows; const int* cols; const float* vals;
    int nnz, shift, nb, chunk_id;
    int* bincnt; int2* st;
    if ((int)blockIdx.x < nc1) {
        rows = rows1; cols = cols1; vals = vals1; nnz = nnz1;
        shift = 7; nb = NB1; chunk_id = blockIdx.x; bincnt = bincnt1; st = st1;
    } else {
        rows = rows2; cols = cols2; vals = vals2; nnz = nnz2;
        shift = 8; nb = NB2; chunk_id = blockIdx.x - nc1; bincnt = bincnt2; st = st2;
    }
    int t = threadIdx.x;
    for (int i = t; i < nb; i += P1B) hist[i] = 0;
    __syncthreads();
    int begin = chunk_id * CHUNK;

    int r[EPT]; int c[EPT]; float v[EPT];
    #pragma unroll
    for (int k = 0; k < EPT; ++k) {
        int idx = begin + k * P1B + t;
        bool ok = idx < nnz;
        r[k] = ok ? rows[idx] : -1;
        c[k] = ok ? cols[idx] : 0;
        v[k] = ok ? vals[idx] : 0.0f;
        if (ok) atomicAdd(&hist[r[k] >> shift], 1);
    }
    __syncthreads();
    for (int i = t; i < nb; i += P1B) {
        int h = hist[i];
        if (h > 0) cur[i] = i * CAP + atomicAdd(&bincnt[i], h);
    }
    __syncthreads();
    #pragma unroll
    for (int k = 0; k < EPT; ++k) {
        if (r[k] >= 0) {
            int b = r[k] >> shift;
            int pos = atomicAdd(&cur[b], 1);       // LDS atomic
            int key = ((r[k] - (b << shift)) << 17) | c[k];
            st[pos] = make_int2(key, __float_as_int(v[k]));
        }
    }
}

__global__ void f32_to_f16_kernel(const float4* __restrict__ in,
                                  int2* __restrict__ outp, int n4) {
    int i = blockIdx.x * blockDim.x + threadIdx.x;
    if (i >= n4) return;
    float4 x = in[i];
    __half2 h0 = __float22half2_rn(make_float2(x.x, x.y));
    __half2 h1 = __float22half2_rn(make_float2(x.z, x.w));
    int2 pk;
    pk.x = *(int*)&h0;
    pk.y = *(int*)&h1;
    outp[i] = pk;
}

// One WG per bin: LDS sort by row, then gather from LDS edge list.
// src is fp16 [n_src,64]; dst is fp16 or fp32 per DST_HALF.
template <int RPB, bool DST_HALF>
__global__ __launch_bounds__(1024, 8) void sort_gather_kernel(
    const int2* __restrict__ st, const int* __restrict__ bincnt,
    const __half* __restrict__ src,
    void* __restrict__ dstv,
    int n_rows) {
    __shared__ int2 edges[CAP];
    __shared__ int excl[RPB];        // row start (within LDS edges[])
    __shared__ int cur[RPB];         // cursor; after scatter = row end
    int b = blockIdx.x;
    int t = threadIdx.x;
    int row0 = b * RPB;
    int cnt_b = bincnt[b];
    const int2* bst = st + (size_t)b * CAP;

    if (t < RPB) cur[t] = 0;
    __syncthreads();
    for (int i = t; i < cnt_b; i += 1024)
        atomicAdd(&cur[bst[i].x >> 17], 1);
    __syncthreads();
    if (t < RPB) excl[t] = cur[t];
    __syncthreads();
    for (int off = 1; off < RPB; off <<= 1) {
        int vv = 0;
        if (t < RPB && t >= off) vv = excl[t - off];
        __syncthreads();
        if (t < RPB) excl[t] += vv;
        __syncthreads();
    }
    if (t < RPB) {
        int e = excl[t] - cur[t];
        excl[t] = e;
        cur[t] = e;
    }
    __syncthreads();
    for (int i = t; i < cnt_b; i += 1024) {
        int2 kv = bst[i];
        int pos = atomicAdd(&cur[kv.x >> 17], 1);   // LDS atomic
        edges[pos] = make_int2(kv.x & 0x1FFFF, kv.y);
    }
    __syncthreads();
    // gather: one wave per row, 16 waves/WG; 8 edges in flight.
    // lane = 16*sub + ld: sub = edge slot, ld = 4-half chunk (8B load).
    int wave = t >> 6;
    int lane = t & 63;
    int sub = lane >> 4;
    int ld  = lane & 15;
    for (int rl = wave; rl < RPB; rl += 16) {
        int row = row0 + rl;
        if (row >= n_rows) break;
        int start = excl[rl];
        int end   = cur[rl];
        float ax = 0.f, ay = 0.f, az = 0.f, aw = 0.f, vsum = 0.f;
        for (int i = start; i < end; i += 8) {
            int i0 = i + sub, i1 = i + sub + 4;
            int c0 = 0, c1 = 0; float v0 = 0.f, v1 = 0.f;
            if (i0 < end) { int2 e = edges[i0]; c0 = e.x; v0 = __int_as_float(e.y); }
            if (i1 < end) { int2 e = edges[i1]; c1 = e.x; v1 = __int_as_float(e.y); }
            int2 r0 = *(const int2*)(src + (long long)c0 * DIM + ld * 4);
            int2 r1 = *(const int2*)(src + (long long)c1 * DIM + ld * 4);
            float2 a0 = __half22float2(*(__half2*)&r0.x);
            float2 b0 = __half22float2(*(__half2*)&r0.y);
            float2 a1 = __half22float2(*(__half2*)&r1.x);
            float2 b1 = __half22float2(*(__half2*)&r1.y);
            ax += v0 * a0.x + v1 * a1.x;
            ay += v0 * a0.y + v1 * a1.y;
            az += v0 * b0.x + v1 * b1.x;
            aw += v0 * b0.y + v1 * b1.y;
            vsum += v0 + v1;
        }
        #pragma unroll
        for (int off = 16; off <= 32; off <<= 1) {
            ax += __shfl_xor(ax, off);
            ay += __shfl_xor(ay, off);
            az += __shfl_xor(az, off);
            aw += __shfl_xor(aw, off);
            vsum += __shfl_xor(vsum, off);
        }
        float d = (vsum == 0.0f) ? 1.0f : vsum;
        if (sub == 0) {
            float inv = 1.0f / d;
            if (DST_HALF) {
                __half* dst = (__half*)dstv;
                __half2 o0 = __float22half2_rn(make_float2(ax * inv, ay * inv));
                __half2 o1 = __float22half2_rn(make_float2(az * inv, aw * inv));
                int2 pk;
                pk.x = *(int*)&o0;
                pk.y = *(int*)&o1;
                *(int2*)(dst + (long long)row * DIM + ld * 4) = pk;
            } else {
                float* dst = (float*)dstv;
                float4 o = make_float4(ax * inv, ay * inv, az * inv, aw * inv);
                *(float4*)(dst + (long long)row * DIM + ld * 4) = o;
            }
        }
    }
}

extern "C" void kernel_launch(void* const* d_in, const int* in_sizes, int n_in,
                              void* d_out, int out_size, void* d_ws, size_t ws_size,
                              hipStream_t stream) {
    const float* item_emb = (const float*)d_in[1];
    const int*   hv_rows  = (const int*)d_in[2];
    const int*   hv_cols  = (const int*)d_in[3];
    const float* hv_vals  = (const float*)d_in[4];
    const int*   hu_rows  = (const int*)d_in[5];
    const int*   hu_cols  = (const int*)d_in[6];
    const float* hu_vals  = (const float*)d_in[7];

    const int nnz1 = in_sizes[2];
    const int nnz2 = in_sizes[5];
    const int n_items = in_sizes[1] / DIM;   // 100000
    const int n_b  = 50000;
    const int n_u  = out_size / DIM;

    float* out = (float*)d_out;

    // Workspace (~56.3 MB)
    char* p = (char*)d_ws;
    __half* item_h  = (__half*)p; p += (size_t)n_items * DIM * sizeof(__half); // 12.8 MB
    __half* bf_h    = (__half*)p; p += (size_t)n_b * DIM * sizeof(__half);     // 6.4 MB
    int*   bincnt1 = (int*)p;   p += 400 * sizeof(int);
    int*   bincnt2 = (int*)p;   p += 400 * sizeof(int);
    int2*  st1     = (int2*)p;  p += (size_t)NB1 * CAP * sizeof(int2);         // 18.4 MB
    int2*  st2     = (int2*)p;  p += (size_t)NB2 * CAP * sizeof(int2);         // 18.4 MB

    hipMemsetAsync(bincnt1, 0, 800 * sizeof(int), stream);

    int n4 = n_items * DIM / 4;
    f32_to_f16_kernel<<<(n4 + 255) / 256, 256, 0, stream>>>(
        (const float4*)item_emb, (int2*)item_h, n4);

    int nc1 = (nnz1 + CHUNK - 1) / CHUNK;
    int nc2 = (nnz2 + CHUNK - 1) / CHUNK;
    pass1_bin_kernel<<<nc1 + nc2, P1B, 0, stream>>>(
        hv_rows, hv_cols, hv_vals, nnz1, nc1,
        hu_rows, hu_cols, hu_vals, nnz2,
        bincnt1, st1, bincnt2, st2);

    // Hop 1: item_h -> bf_h   (50000 rows, 128 rows/bin)
    sort_gather_kernel<128, true><<<NB1, 1024, 0, stream>>>(
        st1, bincnt1, item_h, bf_h, n_b);
    // Hop 2: bf_h -> out      (100000 rows, 256 rows/bin)
    sort_gather_kernel<256, false><<<NB2, 1024, 0, stream>>>(
        st2, bincnt2, bf_h, out, n_u);
}